// Round 19
// baseline (1190.482 us; speedup 1.0000x reference)
//
#include <hip/hip_runtime.h>
#include <math.h>

#define N_ENT 50000
#define N_REL 500
#define DEG 32
#define TOPK 10
#define H_DIM 256
#define N_HEADS 4
#define HEAD_DIM 64
#define NTILE 782   // ceil(50000/64)

typedef __attribute__((ext_vector_type(8))) short short8v;
typedef __attribute__((ext_vector_type(4))) float f32x4;

// ---------------- workspace layout (bytes) ----------------
constexpr size_t OFF_SSRC0 = 0;                      // f64 [N_ENT]
constexpr size_t OFF_SR0   = 400000;                 // f64 [N_REL]
constexpr size_t OFF_U0    = 404000;                 // f64 [256]
constexpr size_t OFF_V0    = 406048;                 // f64 [256]
constexpr size_t OFF_SS    = 408096;                 // f32 [N_ENT][8]
constexpr size_t OFF_SSR   = 2008096;                // f32 [N_REL][8]
constexpr size_t OFF_U8    = 2024096;                // f32 [256][8]
constexpr size_t OFF_V8    = 2032288;                // f32 [256][8]
constexpr size_t OFF_B1H   = 2040480;                // bf16 packed 131072 B each
constexpr size_t OFF_B2H   = 2302624;
constexpr size_t OFF_B3H   = 2564768;
constexpr size_t OFF_NPK   = 3089056;                // bf16 row-major neigh [50048][256]
constexpr size_t OFF_EMBBF = 28713632;               // bf16 [N_ENT][256] emb_t (row-major)
constexpr size_t OFF_RELBF = 54313632;               // bf16 [N_REL][256]
constexpr size_t OFF_CNT   = 54569632;               // u32 [NTILE] tile counters
constexpr size_t WS_NEED   = 54572760;               // ~52 MB

__device__ __forceinline__ float leaky(float x) { return x >= 0.f ? x : 0.2f * x; }

__device__ __forceinline__ unsigned short bf16_rne(float x) {
    unsigned int u = __float_as_uint(x);
    unsigned int r = u + 0x7fffu + ((u >> 16) & 1u);
    return (unsigned short)(r >> 16);
}
__device__ __forceinline__ float bf2f(unsigned short x) {
    return __uint_as_float((unsigned)x << 16);
}

// B-side MFMA-fragment pack offset
__device__ __forceinline__ size_t pack_off(int row, int d) {
    return ((size_t)(row >> 4) * 8 + (d >> 5)) * 512 +
           (((d >> 3) & 3) * 16 + (row & 15)) * 8 + (d & 7);
}

// ---------------- K0: setup (U/V vectors | B splits | counter reset) ----------------
__global__ __launch_bounds__(256) void setup_kernel(
    const float* __restrict__ W, const float* __restrict__ W_r,
    const float* __restrict__ a, const float* __restrict__ nw,
    float* __restrict__ U8, double* __restrict__ u0,
    float* __restrict__ V8, double* __restrict__ v0,
    unsigned short* __restrict__ b1h, unsigned short* __restrict__ b2h,
    unsigned short* __restrict__ b3h, unsigned* __restrict__ cnt)
{
    const int bid = blockIdx.x;
    const int tid = threadIdx.x;
    if (bid == 0) {
        for (int i = tid; i < NTILE; i += 256) cnt[i] = 0u;
        int d = tid;
        #pragma unroll
        for (int h = 0; h < N_HEADS; ++h) {
            float ss = 0.f, sd = 0.f;
            #pragma unroll
            for (int e = 0; e < HEAD_DIM; ++e) {
                float w = W[h * 16384 + d * 64 + e];
                ss += w * a[h * 192 + e];
                sd += w * a[h * 192 + 64 + e];
            }
            U8[d * 8 + h] = ss;
            U8[d * 8 + 4 + h] = sd;
        }
        double s0 = 0.0;
        #pragma unroll
        for (int e = 0; e < HEAD_DIM; ++e)
            s0 += (double)W[d * 64 + e] * (double)a[e];
        u0[d] = s0;
    } else if (bid == 1) {
        int d = tid;
        #pragma unroll
        for (int h = 0; h < N_HEADS; ++h) {
            float sv = 0.f;
            #pragma unroll
            for (int e = 0; e < HEAD_DIM; ++e)
                sv += W_r[h * 16384 + d * 64 + e] * a[h * 192 + 128 + e];
            V8[d * 8 + h] = sv;
            V8[d * 8 + 4 + h] = 0.f;
        }
        double s0 = 0.0;
        #pragma unroll
        for (int e = 0; e < HEAD_DIM; ++e)
            s0 += (double)W_r[d * 64 + e] * (double)a[128 + e];
        v0[d] = s0;
    } else {
        int n = bid - 2;
        int k = tid;
        int h = n >> 6, e = n & 63;
        float x1 = W[h * 16384 + k * 64 + e];
        float x2 = nw[k * 256 + n];
        float x3 = W_r[h * 16384 + k * 64 + e];
        size_t off = pack_off(n, k);
        b1h[off] = bf16_rne(x1);
        b2h[off] = bf16_rne(x2);
        b3h[off] = bf16_rne(x3);
    }
}

// ---------------- K1: single-pass {staging+scores -> MFMA GEMM} ----------------
__global__ __launch_bounds__(256, 3) void mid_kernel(
    const float* __restrict__ ent, const float* __restrict__ relm,
    const unsigned short* __restrict__ b1h, const unsigned short* __restrict__ b3h,
    unsigned short* __restrict__ embbf, unsigned short* __restrict__ relbf,
    const float* __restrict__ U8, const double* __restrict__ u0,
    const float* __restrict__ V8, const double* __restrict__ v0,
    float* __restrict__ SS, double* __restrict__ ssrc0,
    float* __restrict__ SSR, double* __restrict__ sr0)
{
    __shared__ unsigned short As[64][264];

    const int b = blockIdx.x;
    const int tid = threadIdx.x;
    const int l = tid & 63;
    const int el = l & 31;
    const int w = tid >> 6;
    const int rl = l & 15;
    const int ql = l >> 4;

    const bool isent = (b < 782);
    const float* Af = isent ? ent : relm;
    const unsigned short* Bh = isent ? b1h : b3h;
    unsigned short* C = isent ? embbf : relbf;
    const float* U8v = isent ? U8 : V8;
    const double* u0v = isent ? u0 : v0;
    float* SSout = isent ? SS : SSR;
    double* s0out = isent ? ssrc0 : sr0;
    const int M = isent ? N_ENT : N_REL;
    const int bm = (isent ? b : (b - 782)) * 64;

    float uu[8][8];
    #pragma unroll
    for (int i = 0; i < 8; ++i) {
        float4 a4 = *(const float4*)(U8v + (el * 8 + i) * 8);
        float4 b4 = *(const float4*)(U8v + (el * 8 + i) * 8 + 4);
        uu[i][0] = a4.x; uu[i][1] = a4.y; uu[i][2] = a4.z; uu[i][3] = a4.w;
        uu[i][4] = b4.x; uu[i][5] = b4.y; uu[i][6] = b4.z; uu[i][7] = b4.w;
    }
    double ud[8];
    #pragma unroll
    for (int i = 0; i < 8; ++i) ud[i] = u0v[el * 8 + i];

    const int jout = ((el & 1) << 2) | (el & 2) | ((el >> 2) & 1);

    // ---- phase A: stage f32->bf16 into LDS + compute scores per row ----
    #pragma unroll
    for (int i = 0; i < 8; ++i) {
        const int row = i * 8 + (tid >> 5);
        const int grow = min(bm + row, M - 1);
        const float* rp = Af + (size_t)grow * 256 + el * 8;
        float4 v1 = *(const float4*)(rp);
        float4 v2 = *(const float4*)(rp + 4);
        float xs[8] = {v1.x, v1.y, v1.z, v1.w, v2.x, v2.y, v2.z, v2.w};

        short8v ov;
        #pragma unroll
        for (int j = 0; j < 8; ++j) ov[j] = (short)bf16_rne(xs[j]);
        *(short8v*)&As[row][el * 8] = ov;

        float pj[8] = {0.f, 0.f, 0.f, 0.f, 0.f, 0.f, 0.f, 0.f};
        double pd = 0.0;
        #pragma unroll
        for (int ii = 0; ii < 8; ++ii) {
            #pragma unroll
            for (int j = 0; j < 8; ++j) pj[j] += xs[ii] * uu[ii][j];
            pd += (double)xs[ii] * ud[ii];
        }

        const bool b1 = (el & 1);
        float q[4];
        #pragma unroll
        for (int j = 0; j < 4; ++j) {
            float mine = b1 ? pj[j + 4] : pj[j];
            float send = b1 ? pj[j] : pj[j + 4];
            q[j] = mine + __shfl_xor(send, 1);
        }
        const bool b2 = (el & 2);
        float r2[2];
        #pragma unroll
        for (int j = 0; j < 2; ++j) {
            float mine = b2 ? q[j + 2] : q[j];
            float send = b2 ? q[j] : q[j + 2];
            r2[j] = mine + __shfl_xor(send, 2);
        }
        const bool b4 = (el & 4);
        {
            float mine = b4 ? r2[1] : r2[0];
            float send = b4 ? r2[0] : r2[1];
            r2[0] = mine + __shfl_xor(send, 4);
        }
        r2[0] += __shfl_xor(r2[0], 8);
        r2[0] += __shfl_xor(r2[0], 16);

        #pragma unroll
        for (int off = 1; off < 32; off <<= 1) pd += __shfl_xor(pd, off);

        if (el < 8) SSout[(size_t)grow * 8 + jout] = r2[0];
        if (el == 0) s0out[grow] = pd;
    }
    __syncthreads();

    // ---- phase B: MFMA GEMM from LDS A-tile ----
    const unsigned short* bhb = Bh + (size_t)w * 16384 + l * 8;

    f32x4 acc[4][4];
    #pragma unroll
    for (int i = 0; i < 4; ++i)
        #pragma unroll
        for (int j = 0; j < 4; ++j) acc[i][j] = (f32x4){0.f, 0.f, 0.f, 0.f};

    #pragma unroll
    for (int ks = 0; ks < 8; ++ks) {
        short8v ah[4], bh[4];
        #pragma unroll
        for (int mf = 0; mf < 4; ++mf)
            ah[mf] = *(const short8v*)&As[mf * 16 + rl][ks * 32 + ql * 8];
        #pragma unroll
        for (int nf = 0; nf < 4; ++nf)
            bh[nf] = *(const short8v*)(bhb + nf * 4096 + ks * 512);
        #pragma unroll
        for (int mf = 0; mf < 4; ++mf)
            #pragma unroll
            for (int nf = 0; nf < 4; ++nf)
                acc[mf][nf] = __builtin_amdgcn_mfma_f32_16x16x32_bf16(ah[mf], bh[nf], acc[mf][nf], 0, 0, 0);
    }

    #pragma unroll
    for (int mf = 0; mf < 4; ++mf) {
        int row0 = bm + mf * 16 + ql * 4;
        #pragma unroll
        for (int nf = 0; nf < 4; ++nf) {
            int c = w * 64 + nf * 16 + rl;
            #pragma unroll
            for (int j = 0; j < 4; ++j) {
                int r = row0 + j;
                if (r < M)
                    C[(size_t)r * 256 + c] = bf16_rne(acc[mf][nf][j]);
            }
        }
    }
}

// ---------------- K2: fused select + softmax + aggregate + tile-GEMM tail ----------------
// 32 lanes per node, 8 nodes per block (r17 interior). After napk stores, the
// last-finishing block of each 64-row tile computes that tile's output GEMM
// (device-scope counter + threadfence handshake; output bit-identical).
__global__ __launch_bounds__(256, 3) void node_kernel(
    const int* __restrict__ src, const int* __restrict__ relid,
    const float* __restrict__ SS, const double* __restrict__ ssrc0,
    const float* __restrict__ SSR, const double* __restrict__ sr0,
    const unsigned short* __restrict__ emb_bf, const unsigned short* __restrict__ rel_bf,
    unsigned short* __restrict__ napk,
    unsigned* __restrict__ cnt, const unsigned short* __restrict__ b2h,
    float* __restrict__ out)
{
    __shared__ double scs[8][33];
    __shared__ unsigned idsS[8][12];
    __shared__ float wtsS[8][10][4];
    __shared__ float sumsS[8][4];
    __shared__ unsigned short As[64][264];
    __shared__ int lastFlag;

    const int tid = threadIdx.x;
    const int l = tid & 63;
    const int el = l & 31;
    const int hb = l & 32;
    const int nib = tid >> 5;
    const int n = blockIdx.x * 8 + nib;

    const int sd_ = src[n * DEG + el];
    const int rd_ = relid[n * DEG + el];
    const double sc0 = ssrc0[sd_] + sr0[rd_];
    scs[nib][el] = sc0;

    int cntk = 0;
    #pragma unroll
    for (int j = 0; j < DEG; ++j) {
        double sj = scs[nib][j];
        cntk += (sj > sc0 || (sj == sc0 && j < el)) ? 1 : 0;
    }
    const bool sel = (cntk < TOPK);
    const unsigned mask = (unsigned)(__ballot(sel) >> hb);
    const int pos = __popc(mask & ((1u << el) - 1u));

    float ex = 0.f, ey = 0.f, ez = 0.f, ew = 0.f;
    if (sel) {
        float4 ssv = *(const float4*)(SS + (size_t)sd_ * 8);
        float4 srv = *(const float4*)(SSR + (size_t)rd_ * 8);
        float4 sdv = *(const float4*)(SS + (size_t)n * 8 + 4);
        ex = __expf(leaky(ssv.x + sdv.x + srv.x));
        ey = __expf(leaky(ssv.y + sdv.y + srv.y));
        ez = __expf(leaky(ssv.z + sdv.z + srv.z));
        ew = __expf(leaky(ssv.w + sdv.w + srv.w));
        idsS[nib][pos] = (unsigned)sd_ | ((unsigned)rd_ << 16);
        float4 wv; wv.x = ex; wv.y = ey; wv.z = ez; wv.w = ew;
        *(float4*)&wtsS[nib][pos][0] = wv;
    }

    float p0, p1;
    {
        const bool b1 = (el & 1);
        float m0 = b1 ? ez : ex, s0 = b1 ? ex : ez;
        float m1 = b1 ? ew : ey, s1 = b1 ? ey : ew;
        p0 = m0 + __shfl_xor(s0, 1);
        p1 = m1 + __shfl_xor(s1, 1);
    }
    float qsum;
    {
        const bool b2 = (el & 2);
        float m = b2 ? p1 : p0, s = b2 ? p0 : p1;
        qsum = m + __shfl_xor(s, 2);
    }
    qsum += __shfl_xor(qsum, 4);
    qsum += __shfl_xor(qsum, 8);
    qsum += __shfl_xor(qsum, 16);
    if (el < 4) sumsS[nib][((el & 1) << 1) | ((el >> 1) & 1)] = qsum;

    const int h = el >> 3;

    int skA[TOPK], rkA[TOPK];
    #pragma unroll
    for (int k = 0; k < TOPK; ++k) {
        unsigned idk = idsS[nib][k];
        skA[k] = (int)(idk & 0xFFFFu);
        rkA[k] = (int)(idk >> 16);
    }

    short8v ev[TOPK], rv[TOPK];
    #pragma unroll
    for (int k = 0; k < TOPK; ++k)
        ev[k] = *(const short8v*)(emb_bf + (size_t)skA[k] * 256 + el * 8);
    #pragma unroll
    for (int k = 0; k < TOPK; ++k)
        rv[k] = *(const short8v*)(rel_bf + (size_t)rkA[k] * 256 + el * 8);
    asm volatile("s_waitcnt vmcnt(0)" ::: "memory");

    const float rsh = 1.f / sumsS[nib][h];
    float acc8[8] = {0.f, 0.f, 0.f, 0.f, 0.f, 0.f, 0.f, 0.f};
    #pragma unroll
    for (int k = 0; k < TOPK; ++k) {
        float w = wtsS[nib][k][h] * rsh;
        #pragma unroll
        for (int j = 0; j < 8; ++j)
            acc8[j] += w * (bf2f((unsigned short)ev[k][j]) + bf2f((unsigned short)rv[k][j]));
    }

    short8v ov;
    #pragma unroll
    for (int j = 0; j < 8; ++j) ov[j] = (short)bf16_rne(acc8[j]);
    *(short8v*)(napk + (size_t)n * 256 + el * 8) = ov;

    // ---- tile-GEMM tail: last block of each 64-row tile computes the output ----
    __syncthreads();   // all waves' napk stores drained (vmcnt=0 before barrier)
    if (tid == 0) {
        __threadfence();                       // release: push block's writes device-wide
        const int tile = (int)(blockIdx.x >> 3);
        const unsigned target = (tile == NTILE - 1) ? 2u : 8u;
        lastFlag = (atomicAdd(&cnt[tile], 1u) == target - 1u) ? 1 : 0;
    }
    __syncthreads();
    if (!lastFlag) return;
    __threadfence();                           // acquire: see peer blocks' napk writes

    const int w = tid >> 6;
    const int rl = l & 15;
    const int ql = l >> 4;
    const int bm = (int)(blockIdx.x >> 3) * 64;

    const unsigned short* Ag = napk + (size_t)bm * 256;
    #pragma unroll
    for (int i = 0; i < 8; ++i) {
        int u = i * 256 + tid;
        short8v v = *(const short8v*)(Ag + (size_t)u * 8);
        *(short8v*)&As[u >> 5][(u & 31) * 8] = v;
    }
    __syncthreads();

    const unsigned short* bhb = b2h + (size_t)w * 16384 + l * 8;

    f32x4 acc[4][4];
    #pragma unroll
    for (int i = 0; i < 4; ++i)
        #pragma unroll
        for (int j = 0; j < 4; ++j) acc[i][j] = (f32x4){0.f, 0.f, 0.f, 0.f};

    #pragma unroll
    for (int ks = 0; ks < 8; ++ks) {
        short8v ah[4], bh[4];
        #pragma unroll
        for (int mf = 0; mf < 4; ++mf)
            ah[mf] = *(const short8v*)&As[mf * 16 + rl][ks * 32 + ql * 8];
        #pragma unroll
        for (int nf = 0; nf < 4; ++nf)
            bh[nf] = *(const short8v*)(bhb + nf * 4096 + ks * 512);
        #pragma unroll
        for (int mf = 0; mf < 4; ++mf)
            #pragma unroll
            for (int nf = 0; nf < 4; ++nf)
                acc[mf][nf] = __builtin_amdgcn_mfma_f32_16x16x32_bf16(ah[mf], bh[nf], acc[mf][nf], 0, 0, 0);
    }

    #pragma unroll
    for (int mf = 0; mf < 4; ++mf) {
        int row0 = bm + mf * 16 + ql * 4;
        #pragma unroll
        for (int nf = 0; nf < 4; ++nf) {
            int c = w * 64 + nf * 16 + rl;
            #pragma unroll
            for (int j = 0; j < 4; ++j) {
                int r = row0 + j;
                if (r < N_ENT) {
                    float v = acc[mf][nf][j];
                    out[(size_t)r * 256 + c] = 1.f - 2.f / (__expf(2.f * v) + 1.f);
                }
            }
        }
    }
}

extern "C" void kernel_launch(void* const* d_in, const int* in_sizes, int n_in,
                              void* d_out, int out_size, void* d_ws, size_t ws_size,
                              hipStream_t stream) {
    const float* ent  = (const float*)d_in[0];
    const float* rel  = (const float*)d_in[1];
    const float* W    = (const float*)d_in[2];
    const float* W_r  = (const float*)d_in[3];
    const float* a    = (const float*)d_in[4];
    const float* nw   = (const float*)d_in[5];
    const int*   srcp = (const int*)d_in[6];
    const int*   ridp = (const int*)d_in[7];
    float* out = (float*)d_out;

    if (ws_size < WS_NEED) return;

    char* ws = (char*)d_ws;
    double* ssrc0 = (double*)(ws + OFF_SSRC0);
    double* sr0   = (double*)(ws + OFF_SR0);
    double* u0    = (double*)(ws + OFF_U0);
    double* v0    = (double*)(ws + OFF_V0);
    float*  SS    = (float*)(ws + OFF_SS);
    float*  SSR   = (float*)(ws + OFF_SSR);
    float*  U8    = (float*)(ws + OFF_U8);
    float*  V8    = (float*)(ws + OFF_V8);
    unsigned short* b1h = (unsigned short*)(ws + OFF_B1H);
    unsigned short* b2h = (unsigned short*)(ws + OFF_B2H);
    unsigned short* b3h = (unsigned short*)(ws + OFF_B3H);
    unsigned short* napk = (unsigned short*)(ws + OFF_NPK);
    unsigned short* embbf = (unsigned short*)(ws + OFF_EMBBF);
    unsigned short* relbf = (unsigned short*)(ws + OFF_RELBF);
    unsigned* cnt = (unsigned*)(ws + OFF_CNT);

    setup_kernel<<<258, 256, 0, stream>>>(W, W_r, a, nw, U8, u0, V8, v0,
                                          b1h, b2h, b3h, cnt);
    mid_kernel<<<790, 256, 0, stream>>>(ent, rel, b1h, b3h, embbf, relbf,
                                        U8, u0, V8, v0, SS, ssrc0, SSR, sr0);
    node_kernel<<<6250, 256, 0, stream>>>(srcp, ridp, SS, ssrc0, SSR, sr0,
                                          embbf, relbf, napk, cnt, b2h, out);
}

// Round 20
// 124.535 us; speedup vs baseline: 9.5594x; 9.5594x over previous
//
#include <hip/hip_runtime.h>
#include <math.h>

#define N_ENT 50000
#define N_REL 500
#define DEG 32
#define TOPK 10
#define H_DIM 256
#define N_HEADS 4
#define HEAD_DIM 64

typedef __attribute__((ext_vector_type(8))) short short8v;
typedef __attribute__((ext_vector_type(4))) float f32x4;

// ---------------- workspace layout (bytes) ----------------
constexpr size_t OFF_SSRC0 = 0;                      // f64 [N_ENT]
constexpr size_t OFF_SR0   = 400000;                 // f64 [N_REL]
constexpr size_t OFF_U0    = 404000;                 // f64 [256]
constexpr size_t OFF_V0    = 406048;                 // f64 [256]
constexpr size_t OFF_SS    = 408096;                 // f32 [N_ENT][8]
constexpr size_t OFF_SSR   = 2008096;                // f32 [N_REL][8]
constexpr size_t OFF_U8    = 2024096;                // f32 [256][8]
constexpr size_t OFF_V8    = 2032288;                // f32 [256][8]
constexpr size_t OFF_B1H   = 2040480;                // bf16 packed 131072 B each
constexpr size_t OFF_B2H   = 2302624;
constexpr size_t OFF_B3H   = 2564768;
constexpr size_t OFF_NPK   = 3089056;                // bf16 row-major neigh [50048][256]
constexpr size_t OFF_EMBBF = 28713632;               // bf16 [N_ENT][256] emb_t (row-major)
constexpr size_t OFF_RELBF = 54313632;               // bf16 [N_REL][256]
constexpr size_t WS_NEED   = 54569632;               // ~52 MB

__device__ __forceinline__ float leaky(float x) { return x >= 0.f ? x : 0.2f * x; }

__device__ __forceinline__ unsigned short bf16_rne(float x) {
    unsigned int u = __float_as_uint(x);
    unsigned int r = u + 0x7fffu + ((u >> 16) & 1u);
    return (unsigned short)(r >> 16);
}
__device__ __forceinline__ float bf2f(unsigned short x) {
    return __uint_as_float((unsigned)x << 16);
}

// B-side MFMA-fragment pack offset
__device__ __forceinline__ size_t pack_off(int row, int d) {
    return ((size_t)(row >> 4) * 8 + (d >> 5)) * 512 +
           (((d >> 3) & 3) * 16 + (row & 15)) * 8 + (d & 7);
}

// ---------------- K0: setup (U/V vectors | B splits) ----------------
__global__ __launch_bounds__(256) void setup_kernel(
    const float* __restrict__ W, const float* __restrict__ W_r,
    const float* __restrict__ a, const float* __restrict__ nw,
    float* __restrict__ U8, double* __restrict__ u0,
    float* __restrict__ V8, double* __restrict__ v0,
    unsigned short* __restrict__ b1h, unsigned short* __restrict__ b2h,
    unsigned short* __restrict__ b3h)
{
    const int bid = blockIdx.x;
    const int tid = threadIdx.x;
    if (bid == 0) {
        int d = tid;
        #pragma unroll
        for (int h = 0; h < N_HEADS; ++h) {
            float ss = 0.f, sd = 0.f;
            #pragma unroll
            for (int e = 0; e < HEAD_DIM; ++e) {
                float w = W[h * 16384 + d * 64 + e];
                ss += w * a[h * 192 + e];
                sd += w * a[h * 192 + 64 + e];
            }
            U8[d * 8 + h] = ss;
            U8[d * 8 + 4 + h] = sd;
        }
        double s0 = 0.0;
        #pragma unroll
        for (int e = 0; e < HEAD_DIM; ++e)
            s0 += (double)W[d * 64 + e] * (double)a[e];
        u0[d] = s0;
    } else if (bid == 1) {
        int d = tid;
        #pragma unroll
        for (int h = 0; h < N_HEADS; ++h) {
            float sv = 0.f;
            #pragma unroll
            for (int e = 0; e < HEAD_DIM; ++e)
                sv += W_r[h * 16384 + d * 64 + e] * a[h * 192 + 128 + e];
            V8[d * 8 + h] = sv;
            V8[d * 8 + 4 + h] = 0.f;
        }
        double s0 = 0.0;
        #pragma unroll
        for (int e = 0; e < HEAD_DIM; ++e)
            s0 += (double)W_r[d * 64 + e] * (double)a[128 + e];
        v0[d] = s0;
    } else {
        int n = bid - 2;
        int k = tid;
        int h = n >> 6, e = n & 63;
        float x1 = W[h * 16384 + k * 64 + e];
        float x2 = nw[k * 256 + n];
        float x3 = W_r[h * 16384 + k * 64 + e];
        size_t off = pack_off(n, k);
        b1h[off] = bf16_rne(x1);
        b2h[off] = bf16_rne(x2);
        b3h[off] = bf16_rne(x3);
    }
}

// ---------------- K1: single-pass {staging+scores -> MFMA GEMM} ----------------
__global__ __launch_bounds__(256, 3) void mid_kernel(
    const float* __restrict__ ent, const float* __restrict__ relm,
    const unsigned short* __restrict__ b1h, const unsigned short* __restrict__ b3h,
    unsigned short* __restrict__ embbf, unsigned short* __restrict__ relbf,
    const float* __restrict__ U8, const double* __restrict__ u0,
    const float* __restrict__ V8, const double* __restrict__ v0,
    float* __restrict__ SS, double* __restrict__ ssrc0,
    float* __restrict__ SSR, double* __restrict__ sr0)
{
    __shared__ unsigned short As[64][264];

    const int b = blockIdx.x;
    const int tid = threadIdx.x;
    const int l = tid & 63;
    const int el = l & 31;
    const int w = tid >> 6;
    const int rl = l & 15;
    const int ql = l >> 4;

    const bool isent = (b < 782);
    const float* Af = isent ? ent : relm;
    const unsigned short* Bh = isent ? b1h : b3h;
    unsigned short* C = isent ? embbf : relbf;
    const float* U8v = isent ? U8 : V8;
    const double* u0v = isent ? u0 : v0;
    float* SSout = isent ? SS : SSR;
    double* s0out = isent ? ssrc0 : sr0;
    const int M = isent ? N_ENT : N_REL;
    const int bm = (isent ? b : (b - 782)) * 64;

    float uu[8][8];
    #pragma unroll
    for (int i = 0; i < 8; ++i) {
        float4 a4 = *(const float4*)(U8v + (el * 8 + i) * 8);
        float4 b4 = *(const float4*)(U8v + (el * 8 + i) * 8 + 4);
        uu[i][0] = a4.x; uu[i][1] = a4.y; uu[i][2] = a4.z; uu[i][3] = a4.w;
        uu[i][4] = b4.x; uu[i][5] = b4.y; uu[i][6] = b4.z; uu[i][7] = b4.w;
    }
    double ud[8];
    #pragma unroll
    for (int i = 0; i < 8; ++i) ud[i] = u0v[el * 8 + i];

    const int jout = ((el & 1) << 2) | (el & 2) | ((el >> 2) & 1);

    // ---- phase A: stage f32->bf16 into LDS + compute scores per row ----
    #pragma unroll
    for (int i = 0; i < 8; ++i) {
        const int row = i * 8 + (tid >> 5);
        const int grow = min(bm + row, M - 1);
        const float* rp = Af + (size_t)grow * 256 + el * 8;
        float4 v1 = *(const float4*)(rp);
        float4 v2 = *(const float4*)(rp + 4);
        float xs[8] = {v1.x, v1.y, v1.z, v1.w, v2.x, v2.y, v2.z, v2.w};

        short8v ov;
        #pragma unroll
        for (int j = 0; j < 8; ++j) ov[j] = (short)bf16_rne(xs[j]);
        *(short8v*)&As[row][el * 8] = ov;

        float pj[8] = {0.f, 0.f, 0.f, 0.f, 0.f, 0.f, 0.f, 0.f};
        double pd = 0.0;
        #pragma unroll
        for (int ii = 0; ii < 8; ++ii) {
            #pragma unroll
            for (int j = 0; j < 8; ++j) pj[j] += xs[ii] * uu[ii][j];
            pd += (double)xs[ii] * ud[ii];
        }

        const bool b1 = (el & 1);
        float q[4];
        #pragma unroll
        for (int j = 0; j < 4; ++j) {
            float mine = b1 ? pj[j + 4] : pj[j];
            float send = b1 ? pj[j] : pj[j + 4];
            q[j] = mine + __shfl_xor(send, 1);
        }
        const bool b2 = (el & 2);
        float r2[2];
        #pragma unroll
        for (int j = 0; j < 2; ++j) {
            float mine = b2 ? q[j + 2] : q[j];
            float send = b2 ? q[j] : q[j + 2];
            r2[j] = mine + __shfl_xor(send, 2);
        }
        const bool b4 = (el & 4);
        {
            float mine = b4 ? r2[1] : r2[0];
            float send = b4 ? r2[0] : r2[1];
            r2[0] = mine + __shfl_xor(send, 4);
        }
        r2[0] += __shfl_xor(r2[0], 8);
        r2[0] += __shfl_xor(r2[0], 16);

        #pragma unroll
        for (int off = 1; off < 32; off <<= 1) pd += __shfl_xor(pd, off);

        if (el < 8) SSout[(size_t)grow * 8 + jout] = r2[0];
        if (el == 0) s0out[grow] = pd;
    }
    __syncthreads();

    // ---- phase B: MFMA GEMM from LDS A-tile ----
    const unsigned short* bhb = Bh + (size_t)w * 16384 + l * 8;

    f32x4 acc[4][4];
    #pragma unroll
    for (int i = 0; i < 4; ++i)
        #pragma unroll
        for (int j = 0; j < 4; ++j) acc[i][j] = (f32x4){0.f, 0.f, 0.f, 0.f};

    #pragma unroll
    for (int ks = 0; ks < 8; ++ks) {
        short8v ah[4], bh[4];
        #pragma unroll
        for (int mf = 0; mf < 4; ++mf)
            ah[mf] = *(const short8v*)&As[mf * 16 + rl][ks * 32 + ql * 8];
        #pragma unroll
        for (int nf = 0; nf < 4; ++nf)
            bh[nf] = *(const short8v*)(bhb + nf * 4096 + ks * 512);
        #pragma unroll
        for (int mf = 0; mf < 4; ++mf)
            #pragma unroll
            for (int nf = 0; nf < 4; ++nf)
                acc[mf][nf] = __builtin_amdgcn_mfma_f32_16x16x32_bf16(ah[mf], bh[nf], acc[mf][nf], 0, 0, 0);
    }

    #pragma unroll
    for (int mf = 0; mf < 4; ++mf) {
        int row0 = bm + mf * 16 + ql * 4;
        #pragma unroll
        for (int nf = 0; nf < 4; ++nf) {
            int c = w * 64 + nf * 16 + rl;
            #pragma unroll
            for (int j = 0; j < 4; ++j) {
                int r = row0 + j;
                if (r < M)
                    C[(size_t)r * 256 + c] = bf16_rne(acc[mf][nf][j]);
            }
        }
    }
}

// ---------------- K2: fused top-k select + softmax + gather-aggregate ----------------
// 32 lanes per node, 8 nodes per block; no barriers; rank via LDS broadcast;
// no-max softmax; fold-reduced sums; 20-deep fenced gather hoist.
__global__ __launch_bounds__(256, 3) void node_kernel(
    const int* __restrict__ src, const int* __restrict__ relid,
    const float* __restrict__ SS, const double* __restrict__ ssrc0,
    const float* __restrict__ SSR, const double* __restrict__ sr0,
    const unsigned short* __restrict__ emb_bf, const unsigned short* __restrict__ rel_bf,
    unsigned short* __restrict__ napk)
{
    __shared__ double scs[8][33];
    __shared__ unsigned idsS[8][12];
    __shared__ float wtsS[8][10][4];
    __shared__ float sumsS[8][4];

    const int tid = threadIdx.x;
    const int l = tid & 63;
    const int el = l & 31;
    const int hb = l & 32;
    const int nib = tid >> 5;
    const int n = blockIdx.x * 8 + nib;

    const int sd_ = src[n * DEG + el];
    const int rd_ = relid[n * DEG + el];
    const double sc0 = ssrc0[sd_] + sr0[rd_];
    scs[nib][el] = sc0;

    int cnt = 0;
    #pragma unroll
    for (int j = 0; j < DEG; ++j) {
        double sj = scs[nib][j];
        cnt += (sj > sc0 || (sj == sc0 && j < el)) ? 1 : 0;
    }
    const bool sel = (cnt < TOPK);
    const unsigned mask = (unsigned)(__ballot(sel) >> hb);
    const int pos = __popc(mask & ((1u << el) - 1u));

    float ex = 0.f, ey = 0.f, ez = 0.f, ew = 0.f;
    if (sel) {
        float4 ssv = *(const float4*)(SS + (size_t)sd_ * 8);
        float4 srv = *(const float4*)(SSR + (size_t)rd_ * 8);
        float4 sdv = *(const float4*)(SS + (size_t)n * 8 + 4);
        ex = __expf(leaky(ssv.x + sdv.x + srv.x));
        ey = __expf(leaky(ssv.y + sdv.y + srv.y));
        ez = __expf(leaky(ssv.z + sdv.z + srv.z));
        ew = __expf(leaky(ssv.w + sdv.w + srv.w));
        idsS[nib][pos] = (unsigned)sd_ | ((unsigned)rd_ << 16);
        float4 wv; wv.x = ex; wv.y = ey; wv.z = ez; wv.w = ew;
        *(float4*)&wtsS[nib][pos][0] = wv;
    }

    float p0, p1;
    {
        const bool b1 = (el & 1);
        float m0 = b1 ? ez : ex, s0 = b1 ? ex : ez;
        float m1 = b1 ? ew : ey, s1 = b1 ? ey : ew;
        p0 = m0 + __shfl_xor(s0, 1);
        p1 = m1 + __shfl_xor(s1, 1);
    }
    float qsum;
    {
        const bool b2 = (el & 2);
        float m = b2 ? p1 : p0, s = b2 ? p0 : p1;
        qsum = m + __shfl_xor(s, 2);
    }
    qsum += __shfl_xor(qsum, 4);
    qsum += __shfl_xor(qsum, 8);
    qsum += __shfl_xor(qsum, 16);
    if (el < 4) sumsS[nib][((el & 1) << 1) | ((el >> 1) & 1)] = qsum;

    const int h = el >> 3;

    int skA[TOPK], rkA[TOPK];
    #pragma unroll
    for (int k = 0; k < TOPK; ++k) {
        unsigned idk = idsS[nib][k];
        skA[k] = (int)(idk & 0xFFFFu);
        rkA[k] = (int)(idk >> 16);
    }

    short8v ev[TOPK], rv[TOPK];
    #pragma unroll
    for (int k = 0; k < TOPK; ++k)
        ev[k] = *(const short8v*)(emb_bf + (size_t)skA[k] * 256 + el * 8);
    #pragma unroll
    for (int k = 0; k < TOPK; ++k)
        rv[k] = *(const short8v*)(rel_bf + (size_t)rkA[k] * 256 + el * 8);
    asm volatile("s_waitcnt vmcnt(0)" ::: "memory");

    const float rsh = 1.f / sumsS[nib][h];
    float acc[8] = {0.f, 0.f, 0.f, 0.f, 0.f, 0.f, 0.f, 0.f};
    #pragma unroll
    for (int k = 0; k < TOPK; ++k) {
        float w = wtsS[nib][k][h] * rsh;
        #pragma unroll
        for (int j = 0; j < 8; ++j)
            acc[j] += w * (bf2f((unsigned short)ev[k][j]) + bf2f((unsigned short)rv[k][j]));
    }

    short8v ov;
    #pragma unroll
    for (int j = 0; j < 8; ++j) ov[j] = (short)bf16_rne(acc[j]);
    *(short8v*)(napk + (size_t)n * 256 + el * 8) = ov;
}

// ---------------- K3: MFMA GEMM, row-major A staged to LDS, B hi packed, f32 tanh out ----------------
__global__ __launch_bounds__(256, 4) void gemm_out(
    const unsigned short* __restrict__ A, const unsigned short* __restrict__ Bpkh,
    float* __restrict__ Cout, int M)
{
    __shared__ unsigned short As[64][264];

    const int tid = threadIdx.x;
    const int l = tid & 63;
    const int w = tid >> 6;
    const int bm = blockIdx.x * 64;
    const int rl = l & 15;
    const int ql = l >> 4;

    const unsigned short* Ag = A + (size_t)bm * 256;
    #pragma unroll
    for (int i = 0; i < 8; ++i) {
        int u = i * 256 + tid;
        short8v v = *(const short8v*)(Ag + (size_t)u * 8);
        *(short8v*)&As[u >> 5][(u & 31) * 8] = v;
    }
    __syncthreads();

    const unsigned short* bhb = Bpkh + (size_t)w * 16384 + l * 8;

    f32x4 acc[4][4];
    #pragma unroll
    for (int i = 0; i < 4; ++i)
        #pragma unroll
        for (int j = 0; j < 4; ++j) acc[i][j] = (f32x4){0.f, 0.f, 0.f, 0.f};

    #pragma unroll
    for (int ks = 0; ks < 8; ++ks) {
        short8v ah[4], bh[4];
        #pragma unroll
        for (int mf = 0; mf < 4; ++mf)
            ah[mf] = *(const short8v*)&As[mf * 16 + rl][ks * 32 + ql * 8];
        #pragma unroll
        for (int nf = 0; nf < 4; ++nf)
            bh[nf] = *(const short8v*)(bhb + nf * 4096 + ks * 512);
        #pragma unroll
        for (int mf = 0; mf < 4; ++mf)
            #pragma unroll
            for (int nf = 0; nf < 4; ++nf)
                acc[mf][nf] = __builtin_amdgcn_mfma_f32_16x16x32_bf16(ah[mf], bh[nf], acc[mf][nf], 0, 0, 0);
    }

    #pragma unroll
    for (int mf = 0; mf < 4; ++mf) {
        int row0 = bm + mf * 16 + ql * 4;
        #pragma unroll
        for (int nf = 0; nf < 4; ++nf) {
            int c = w * 64 + nf * 16 + rl;
            #pragma unroll
            for (int j = 0; j < 4; ++j) {
                int r = row0 + j;
                if (r < M) {
                    float v = acc[mf][nf][j];
                    Cout[(size_t)r * 256 + c] = 1.f - 2.f / (__expf(2.f * v) + 1.f);
                }
            }
        }
    }
}

extern "C" void kernel_launch(void* const* d_in, const int* in_sizes, int n_in,
                              void* d_out, int out_size, void* d_ws, size_t ws_size,
                              hipStream_t stream) {
    const float* ent  = (const float*)d_in[0];
    const float* rel  = (const float*)d_in[1];
    const float* W    = (const float*)d_in[2];
    const float* W_r  = (const float*)d_in[3];
    const float* a    = (const float*)d_in[4];
    const float* nw   = (const float*)d_in[5];
    const int*   srcp = (const int*)d_in[6];
    const int*   ridp = (const int*)d_in[7];
    float* out = (float*)d_out;

    if (ws_size < WS_NEED) return;

    char* ws = (char*)d_ws;
    double* ssrc0 = (double*)(ws + OFF_SSRC0);
    double* sr0   = (double*)(ws + OFF_SR0);
    double* u0    = (double*)(ws + OFF_U0);
    double* v0    = (double*)(ws + OFF_V0);
    float*  SS    = (float*)(ws + OFF_SS);
    float*  SSR   = (float*)(ws + OFF_SSR);
    float*  U8    = (float*)(ws + OFF_U8);
    float*  V8    = (float*)(ws + OFF_V8);
    unsigned short* b1h = (unsigned short*)(ws + OFF_B1H);
    unsigned short* b2h = (unsigned short*)(ws + OFF_B2H);
    unsigned short* b3h = (unsigned short*)(ws + OFF_B3H);
    unsigned short* napk = (unsigned short*)(ws + OFF_NPK);
    unsigned short* embbf = (unsigned short*)(ws + OFF_EMBBF);
    unsigned short* relbf = (unsigned short*)(ws + OFF_RELBF);

    setup_kernel<<<258, 256, 0, stream>>>(W, W_r, a, nw, U8, u0, V8, v0,
                                          b1h, b2h, b3h);
    mid_kernel<<<790, 256, 0, stream>>>(ent, rel, b1h, b3h, embbf, relbf,
                                        U8, u0, V8, v0, SS, ssrc0, SSR, sr0);
    node_kernel<<<6250, 256, 0, stream>>>(srcp, ridp, SS, ssrc0, SSR, sr0,
                                          embbf, relbf, napk);
    gemm_out<<<782, 256, 0, stream>>>(napk, b2h, out, N_ENT);
}